// Round 1
// baseline (116.850 us; speedup 1.0000x reference)
//
#include <hip/hip_runtime.h>
#include <cstdint>
#include <cstddef>

#define ALPHA_ 0.25f
#define CLAMP_ 1e-4f

static constexpr int BLK = 256;

// ws layout (bytes):
//     0 : conf_u[32]   (uint bits of float, atomicMax)
//   128 : vmax_u[32]
//   256 : partial[4096] floats
// 16640 : maskbits[N] uints
static constexpr size_t OFF_VMAX = 128;
static constexpr size_t OFF_PART = 256;
static constexpr size_t OFF_BITS = 16640;

__global__ void k_init(unsigned int* hdr) {
    int t = threadIdx.x;
    if (t < 64) hdr[t] = 0u;  // conf_u[32] + vmax_u[32]
}

__device__ inline unsigned int mask_from_row(const int* __restrict__ boxes, size_t i) {
    const int4* row = (const int4*)(boxes + i * 32);
    unsigned int m = 0u;
#pragma unroll
    for (int q = 0; q < 8; ++q) {
        int4 v = row[q];
        m |= (v.x > 0 ? 1u : 0u) << (4 * q + 0);
        m |= (v.y > 0 ? 1u : 0u) << (4 * q + 1);
        m |= (v.z > 0 ? 1u : 0u) << (4 * q + 2);
        m |= (v.w > 0 ? 1u : 0u) << (4 * q + 3);
    }
    return m;
}

// Pass 1: read boxes (128MB) + scores; write bitmask; conf[g] = max masked score per column.
__global__ void k_pass1(const int* __restrict__ boxes, const float* __restrict__ scores,
                        unsigned int* __restrict__ maskbits, unsigned int* __restrict__ conf_u,
                        int n, int writebits) {
    __shared__ unsigned int sconf[32];
    const int t = threadIdx.x;
    if (t < 32) sconf[t] = 0u;
    __syncthreads();
    const int lane = t & 63;
    unsigned int part = 0u;
    const size_t stride = (size_t)gridDim.x * blockDim.x;
    const size_t wbase0 = (size_t)blockIdx.x * blockDim.x + (size_t)(t - lane);
    for (size_t base = wbase0; base < (size_t)n; base += stride) {  // wave-uniform trip count
        const size_t i = base + (size_t)lane;
        const bool act = i < (size_t)n;
        unsigned int m = 0u;
        float s = 0.0f;
        if (act) {
            m = mask_from_row(boxes, i);
            if (writebits) maskbits[i] = m;
            s = scores[i];
        }
#pragma unroll
        for (int g = 0; g < 32; ++g) {
            float v = ((m >> g) & 1u) ? s : 0.0f;  // scores >= 0, identity 0 safe
#pragma unroll
            for (int off = 32; off > 0; off >>= 1) v = fmaxf(v, __shfl_xor(v, off));
            if (lane == g) {
                unsigned int b = __float_as_uint(v);
                if (b > part) part = b;
            }
        }
    }
    if (lane < 32) atomicMax(&sconf[lane], part);
    __syncthreads();
    if (t < 32) atomicMax(&conf_u[t], sconf[t]);
}

// Pass 2: vmax[g] = max over masked i of s^conf[g] * iou.
template <bool USEBITS>
__global__ void k_pass2(const unsigned int* __restrict__ maskbits, const int* __restrict__ boxes,
                        const float* __restrict__ scores, const float* __restrict__ ious,
                        const unsigned int* __restrict__ conf_u, unsigned int* __restrict__ vmax_u,
                        int n) {
    __shared__ float sconf[32];
    __shared__ unsigned int svmax[32];
    const int t = threadIdx.x;
    if (t < 32) {
        sconf[t] = __uint_as_float(conf_u[t]);
        svmax[t] = 0u;
    }
    __syncthreads();
    float cf[32];
#pragma unroll
    for (int g = 0; g < 32; ++g) cf[g] = sconf[g];
    const int lane = t & 63;
    unsigned int part = 0u;
    const size_t stride = (size_t)gridDim.x * blockDim.x;
    const size_t wbase0 = (size_t)blockIdx.x * blockDim.x + (size_t)(t - lane);
    for (size_t base = wbase0; base < (size_t)n; base += stride) {
        const size_t i = base + (size_t)lane;
        const bool act = i < (size_t)n;
        unsigned int m = 0u;
        float ls = 0.0f, iou = 0.0f;
        if (act) {
            m = USEBITS ? maskbits[i] : mask_from_row(boxes, i);
            if (m) {
                ls = __logf(scores[i]);
                iou = ious[i];
            }
        }
#pragma unroll
        for (int g = 0; g < 32; ++g) {
            float v = ((m >> g) & 1u) ? __expf(cf[g] * ls) * iou : 0.0f;
#pragma unroll
            for (int off = 32; off > 0; off >>= 1) v = fmaxf(v, __shfl_xor(v, off));
            if (lane == g) {
                unsigned int b = __float_as_uint(v);
                if (b > part) part = b;
            }
        }
    }
    if (lane < 32) atomicMax(&svmax[lane], part);
    __syncthreads();
    if (t < 32) atomicMax(&vmax_u[t], svmax[t]);
}

// Pass 3: per-row loss terms, block partial sums (deterministic, no float atomics).
template <bool USEBITS>
__global__ void k_pass3(const unsigned int* __restrict__ maskbits, const int* __restrict__ boxes,
                        const float* __restrict__ scores, const float* __restrict__ ious,
                        const float* __restrict__ logits, const unsigned int* __restrict__ conf_u,
                        const unsigned int* __restrict__ vmax_u, float* __restrict__ partial,
                        int n) {
    __shared__ float sconf[32], srinv[32];
    __shared__ float swsum[BLK / 64];
    const int t = threadIdx.x;
    if (t < 32) {
        sconf[t] = __uint_as_float(conf_u[t]);
        float vm = __uint_as_float(vmax_u[t]);
        srinv[t] = 1.0f / (vm + CLAMP_);
    }
    __syncthreads();
    float cf[32], rv[32];
#pragma unroll
    for (int g = 0; g < 32; ++g) {
        cf[g] = sconf[g];
        rv[g] = srinv[g];
    }
    float accpos = 0.0f;  // sum of logp*sum1 + log1mp*sum2  (to be * -ALPHA)
    float accneg = 0.0f;  // sum of -log(1-p)*p^2 over empty rows (to be * (1-ALPHA))
    const size_t stride = (size_t)gridDim.x * blockDim.x;
    for (size_t i = (size_t)blockIdx.x * blockDim.x + t; i < (size_t)n; i += stride) {
        unsigned int m = USEBITS ? maskbits[i] : mask_from_row(boxes, i);
        float x = logits[i];
        float p = 1.0f / (1.0f + __expf(-x));
        p = fminf(fmaxf(p, CLAMP_), 1.0f - CLAMP_);
        float q = 1.0f - p;
        float log1mp = __logf(q);
        if (m == 0u) {
            accneg += -log1mp * p * p;
        } else {
            float logp = __logf(p);
            float ls = __logf(scores[i]);
            float iou = ious[i];
            float sum1 = 0.0f, sum2 = 0.0f;
#pragma unroll
            for (int g = 0; g < 32; ++g) {
                if ((m >> g) & 1u) {
                    float val = __expf(cf[g] * ls) * iou;
                    float w = (val + CLAMP_) * rv[g];
                    w = fminf(fmaxf(w, CLAMP_), 1.0f - CLAMP_);
                    float a = w * q;
                    float b = (1.0f - w) * p;
                    sum1 += a * a;
                    sum2 += b * b;
                }
            }
            accpos += logp * sum1 + log1mp * sum2;
        }
    }
    float tot = (1.0f - ALPHA_) * accneg - ALPHA_ * accpos;
#pragma unroll
    for (int off = 32; off > 0; off >>= 1) tot += __shfl_xor(tot, off);
    if ((t & 63) == 0) swsum[t >> 6] = tot;
    __syncthreads();
    if (t == 0) {
        float s = 0.0f;
#pragma unroll
        for (int w = 0; w < BLK / 64; ++w) s += swsum[w];
        partial[blockIdx.x] = s;
    }
}

__global__ void k_final(const float* __restrict__ partial, int nb,
                        const unsigned int* __restrict__ npos_raw, float* __restrict__ out) {
    __shared__ float sw[BLK / 64];
    const int t = threadIdx.x;
    float s = 0.0f;
    for (int i = t; i < nb; i += blockDim.x) s += partial[i];
#pragma unroll
    for (int off = 32; off > 0; off >>= 1) s += __shfl_xor(s, off);
    if ((t & 63) == 0) sw[t >> 6] = s;
    __syncthreads();
    if (t == 0) {
        float tot = 0.0f;
#pragma unroll
        for (int w = 0; w < BLK / 64; ++w) tot += sw[w];
        unsigned int v = *npos_raw;
        // int32 if exponent bits are clear (small int), else float32 bits
        float np = (v & 0x7f800000u) ? __uint_as_float(v) : (float)(int)v;
        out[0] = tot / np;
    }
}

extern "C" void kernel_launch(void* const* d_in, const int* in_sizes, int n_in,
                              void* d_out, int out_size, void* d_ws, size_t ws_size,
                              hipStream_t stream) {
    const float* logits = (const float*)d_in[0];
    const float* scores = (const float*)d_in[1];
    const float* ious = (const float*)d_in[2];
    const int* boxes = (const int*)d_in[3];
    // d_in[4] = gt_labels (all zeros; scores/IoUMap have a single column) -> ignored
    const unsigned int* npos_raw = (const unsigned int*)d_in[5];
    float* out = (float*)d_out;
    const int n = in_sizes[0];

    unsigned char* ws = (unsigned char*)d_ws;
    unsigned int* conf_u = (unsigned int*)ws;
    unsigned int* vmax_u = (unsigned int*)(ws + OFF_VMAX);
    float* partial = (float*)(ws + OFF_PART);
    unsigned int* maskbits = (unsigned int*)(ws + OFF_BITS);
    const bool usebits = ws_size >= OFF_BITS + (size_t)n * 4u;

    int nbfull = (n + BLK - 1) / BLK;
    int nb1 = nbfull < 2048 ? nbfull : 2048;
    int nb2 = nb1;
    int nb3 = nb1;  // <= 4096 partial slots

    k_init<<<dim3(1), dim3(64), 0, stream>>>(conf_u);
    k_pass1<<<dim3(nb1), dim3(BLK), 0, stream>>>(boxes, scores, maskbits, conf_u, n,
                                                 usebits ? 1 : 0);
    if (usebits) {
        k_pass2<true><<<dim3(nb2), dim3(BLK), 0, stream>>>(maskbits, boxes, scores, ious, conf_u,
                                                           vmax_u, n);
        k_pass3<true><<<dim3(nb3), dim3(BLK), 0, stream>>>(maskbits, boxes, scores, ious, logits,
                                                           conf_u, vmax_u, partial, n);
    } else {
        k_pass2<false><<<dim3(nb2), dim3(BLK), 0, stream>>>(maskbits, boxes, scores, ious, conf_u,
                                                            vmax_u, n);
        k_pass3<false><<<dim3(nb3), dim3(BLK), 0, stream>>>(maskbits, boxes, scores, ious, logits,
                                                            conf_u, vmax_u, partial, n);
    }
    k_final<<<dim3(1), dim3(BLK), 0, stream>>>(partial, nb3, npos_raw, out);
}